// Round 1
// baseline (898.978 us; speedup 1.0000x reference)
//
#include <hip/hip_runtime.h>

#define D 64
#define NCLS 10
#define NG 128

// ---- degree: deg[dst[e]] += 1 for each edge (self-loop added as +1 later) ----
__global__ void k_deg(const int* __restrict__ dst, int E, int* __restrict__ deg) {
    int e = blockIdx.x * blockDim.x + threadIdx.x;
    if (e < E) atomicAdd(&deg[dst[e]], 1);
}

// ---- h = x @ W1 ; dinv = rsqrt(deg+1) ; acc = h * dinv^2 (self-loop term) ----
__global__ void k_xw1(const float* __restrict__ x, const float* __restrict__ W1,
                      const int* __restrict__ deg, int N,
                      float* __restrict__ h, float* __restrict__ dinv,
                      float* __restrict__ acc) {
    __shared__ float w[D * D];
    int tid = threadIdx.x;
    for (int i = tid; i < D * D; i += blockDim.x) w[i] = W1[i];
    __syncthreads();
    int row = blockIdx.x * 4 + (tid >> 6);
    int col = tid & 63;
    if (row >= N) return;
    const float* xr = x + (size_t)row * D;
    float s = 0.f;
#pragma unroll
    for (int k = 0; k < D; ++k) s += xr[k] * w[k * D + col];
    float d = rsqrtf((float)(deg[row] + 1));
    h[(size_t)row * D + col] = s;
    acc[(size_t)row * D + col] = s * d * d;
    if (col == 0) dinv[row] = d;
}

// ---- edge aggregation: one wave per edge, lane = channel ----
__global__ void k_edge(const int* __restrict__ src, const int* __restrict__ dst, int E,
                       const float* __restrict__ h, const float* __restrict__ dinv,
                       float* __restrict__ acc) {
    int wid = (blockIdx.x * blockDim.x + threadIdx.x) >> 6;
    int lane = threadIdx.x & 63;
    if (wid >= E) return;
    int s = src[wid];
    int t = dst[wid];
    float norm = dinv[s] * dinv[t];
    float v = h[(size_t)s * D + lane] * norm;
    atomicAdd(&acc[(size_t)t * D + lane], v);
}

// ---- relu(acc + b1), mean-pool partial sums via atomics ----
__global__ void k_pool(const float* __restrict__ acc, const float* __restrict__ b1,
                       const int* __restrict__ batch, int N,
                       float* __restrict__ gsum, float* __restrict__ gcnt) {
    int wid = (blockIdx.x * blockDim.x + threadIdx.x) >> 6;
    int lane = threadIdx.x & 63;
    if (wid >= N) return;
    int g = batch[wid];
    float v = acc[(size_t)wid * D + lane] + b1[lane];
    v = v > 0.f ? v : 0.f;
    atomicAdd(&gsum[g * D + lane], v);
    if (lane == 0) atomicAdd(&gcnt[g], 1.0f);
}

// ---- head: hG = gsum/cnt ; logits = hG@W2 + b2 ; log_softmax ----
__global__ void k_head(const float* __restrict__ gsum, const float* __restrict__ gcnt,
                       const float* __restrict__ W2, const float* __restrict__ b2,
                       float* __restrict__ out) {
    int g = threadIdx.x;  // 128 threads, one graph each
    if (g >= NG) return;
    float cnt = gcnt[g];
    cnt = cnt > 1.f ? cnt : 1.f;
    float inv = 1.f / cnt;
    float logits[NCLS];
#pragma unroll
    for (int c = 0; c < NCLS; ++c) logits[c] = b2[c];
    for (int k = 0; k < D; ++k) {
        float hk = gsum[g * D + k] * inv;
#pragma unroll
        for (int c = 0; c < NCLS; ++c) logits[c] += hk * W2[k * NCLS + c];
    }
    float m = logits[0];
#pragma unroll
    for (int c = 1; c < NCLS; ++c) m = fmaxf(m, logits[c]);
    float se = 0.f;
#pragma unroll
    for (int c = 0; c < NCLS; ++c) se += expf(logits[c] - m);
    float lse = m + logf(se);
#pragma unroll
    for (int c = 0; c < NCLS; ++c) out[g * NCLS + c] = logits[c] - lse;
}

extern "C" void kernel_launch(void* const* d_in, const int* in_sizes, int n_in,
                              void* d_out, int out_size, void* d_ws, size_t ws_size,
                              hipStream_t stream) {
    const float* x     = (const float*)d_in[0];
    const int*   ei    = (const int*)d_in[1];   // [2, E] row-major: src then dst
    const int*   batch = (const int*)d_in[2];
    const float* W1    = (const float*)d_in[3];
    const float* b1    = (const float*)d_in[4];
    const float* W2    = (const float*)d_in[5];
    const float* b2    = (const float*)d_in[6];
    float* out = (float*)d_out;

    const int N = in_sizes[0] / D;   // 100000
    const int E = in_sizes[1] / 2;   // 1000000

    char* w = (char*)d_ws;
    float* h    = (float*)w;  w += (size_t)N * D * 4;
    float* acc  = (float*)w;  w += (size_t)N * D * 4;
    int*   deg  = (int*)w;    w += (size_t)N * 4;
    float* dinv = (float*)w;  w += (size_t)N * 4;
    float* gsum = (float*)w;  w += (size_t)NG * D * 4;
    float* gcnt = (float*)w;  w += (size_t)NG * 4;

    // zero the accumulators we rely on (ws is poisoned, not re-zeroed by harness)
    hipMemsetAsync(deg, 0, (size_t)N * 4, stream);
    hipMemsetAsync(gsum, 0, (size_t)(NG * D + NG) * 4, stream);  // gsum + gcnt contiguous

    k_deg<<<(E + 255) / 256, 256, 0, stream>>>(ei + E, E, deg);
    k_xw1<<<(N + 3) / 4, 256, 0, stream>>>(x, W1, deg, N, h, dinv, acc);
    {
        long long threads = (long long)E * 64;
        int blocks = (int)((threads + 255) / 256);
        k_edge<<<blocks, 256, 0, stream>>>(ei, ei + E, E, h, dinv, acc);
    }
    {
        long long threads = (long long)N * 64;
        int blocks = (int)((threads + 255) / 256);
        k_pool<<<blocks, 256, 0, stream>>>(acc, b1, batch, N, gsum, gcnt);
    }
    k_head<<<1, 128, 0, stream>>>(gsum, gcnt, W2, b2, out);
}

// Round 2
// 395.285 us; speedup vs baseline: 2.2742x; 2.2742x over previous
//
#include <hip/hip_runtime.h>

#define D 64
#define NCLS 10
#define NG 128
#define NPW 64  // nodes per wave in k_pool

// ---- degree: deg[dst[e]] += 1 for each edge (self-loop added as +1 later) ----
__global__ void k_deg(const int* __restrict__ dst, int E, int* __restrict__ deg) {
    int e = blockIdx.x * blockDim.x + threadIdx.x;
    if (e < E) atomicAdd(&deg[dst[e]], 1);
}

// ---- h = x @ W1 ; dinv = rsqrt(deg+1) ; acc = h * dinv^2 (self-loop term) ----
__global__ void k_xw1(const float* __restrict__ x, const float* __restrict__ W1,
                      const int* __restrict__ deg, int N,
                      float* __restrict__ h, float* __restrict__ dinv,
                      float* __restrict__ acc) {
    __shared__ float w[D * D];
    int tid = threadIdx.x;
    for (int i = tid; i < D * D; i += blockDim.x) w[i] = W1[i];
    __syncthreads();
    int row = blockIdx.x * 4 + (tid >> 6);
    int col = tid & 63;
    if (row >= N) return;
    const float* xr = x + (size_t)row * D;
    float s = 0.f;
#pragma unroll
    for (int k = 0; k < D; ++k) s += xr[k] * w[k * D + col];
    float d = rsqrtf((float)(deg[row] + 1));
    h[(size_t)row * D + col] = s;
    acc[(size_t)row * D + col] = s * d * d;
    if (col == 0) dinv[row] = d;
}

// ---- edge aggregation: one wave per edge, lane = channel ----
__global__ void k_edge(const int* __restrict__ src, const int* __restrict__ dst, int E,
                       const float* __restrict__ h, const float* __restrict__ dinv,
                       float* __restrict__ acc) {
    int wid = (blockIdx.x * blockDim.x + threadIdx.x) >> 6;
    int lane = threadIdx.x & 63;
    if (wid >= E) return;
    int s = src[wid];
    int t = dst[wid];
    float norm = dinv[s] * dinv[t];
    float v = h[(size_t)s * D + lane] * norm;
    atomicAdd(&acc[(size_t)t * D + lane], v);
}

// ---- relu(acc + b1) + mean-pool: sorted-batch run accumulation, flush on boundary ----
// Wave covers NPW contiguous nodes; lane = (sub-row, float4 slice). Private float4
// accumulator per lane; atomics only when the lane's stream crosses a graph boundary.
__global__ void k_pool(const float* __restrict__ acc, const float* __restrict__ b1,
                       const int* __restrict__ batch, int N,
                       float* __restrict__ gsum, float* __restrict__ gcnt) {
    int wid = (blockIdx.x * blockDim.x + threadIdx.x) >> 6;
    int lane = threadIdx.x & 63;
    int sub = lane >> 4;       // which of 4 interleaved rows
    int c4  = lane & 15;       // float4 slice within a row (channels c4*4 .. c4*4+3)
    int start = wid * NPW;
    if (start >= N) return;
    int end = min(start + NPW, N);
    const float4* acc4 = (const float4*)acc;
    float4 b = ((const float4*)b1)[c4];
    float4 sum = make_float4(0.f, 0.f, 0.f, 0.f);
    float cnt = 0.f;
    int cur_g = -1;
    for (int i = start + sub; i < end; i += 4) {
        int g = batch[i];
        if (g != cur_g) {
            if (cur_g >= 0) {
                float* gs = &gsum[cur_g * D + c4 * 4];
                atomicAdd(gs + 0, sum.x);
                atomicAdd(gs + 1, sum.y);
                atomicAdd(gs + 2, sum.z);
                atomicAdd(gs + 3, sum.w);
                if (c4 == 0) atomicAdd(&gcnt[cur_g], cnt);
            }
            sum = make_float4(0.f, 0.f, 0.f, 0.f);
            cnt = 0.f;
            cur_g = g;
        }
        float4 v = acc4[(size_t)i * (D / 4) + c4];
        sum.x += fmaxf(v.x + b.x, 0.f);
        sum.y += fmaxf(v.y + b.y, 0.f);
        sum.z += fmaxf(v.z + b.z, 0.f);
        sum.w += fmaxf(v.w + b.w, 0.f);
        cnt += 1.f;
    }
    if (cur_g >= 0) {
        float* gs = &gsum[cur_g * D + c4 * 4];
        atomicAdd(gs + 0, sum.x);
        atomicAdd(gs + 1, sum.y);
        atomicAdd(gs + 2, sum.z);
        atomicAdd(gs + 3, sum.w);
        if (c4 == 0) atomicAdd(&gcnt[cur_g], cnt);
    }
}

// ---- head: hG = gsum/cnt ; logits = hG@W2 + b2 ; log_softmax ----
__global__ void k_head(const float* __restrict__ gsum, const float* __restrict__ gcnt,
                       const float* __restrict__ W2, const float* __restrict__ b2,
                       float* __restrict__ out) {
    int g = threadIdx.x;  // 128 threads, one graph each
    if (g >= NG) return;
    float cnt = gcnt[g];
    cnt = cnt > 1.f ? cnt : 1.f;
    float inv = 1.f / cnt;
    float logits[NCLS];
#pragma unroll
    for (int c = 0; c < NCLS; ++c) logits[c] = b2[c];
    for (int k = 0; k < D; ++k) {
        float hk = gsum[g * D + k] * inv;
#pragma unroll
        for (int c = 0; c < NCLS; ++c) logits[c] += hk * W2[k * NCLS + c];
    }
    float m = logits[0];
#pragma unroll
    for (int c = 1; c < NCLS; ++c) m = fmaxf(m, logits[c]);
    float se = 0.f;
#pragma unroll
    for (int c = 0; c < NCLS; ++c) se += expf(logits[c] - m);
    float lse = m + logf(se);
#pragma unroll
    for (int c = 0; c < NCLS; ++c) out[g * NCLS + c] = logits[c] - lse;
}

extern "C" void kernel_launch(void* const* d_in, const int* in_sizes, int n_in,
                              void* d_out, int out_size, void* d_ws, size_t ws_size,
                              hipStream_t stream) {
    const float* x     = (const float*)d_in[0];
    const int*   ei    = (const int*)d_in[1];   // [2, E] row-major: src then dst
    const int*   batch = (const int*)d_in[2];
    const float* W1    = (const float*)d_in[3];
    const float* b1    = (const float*)d_in[4];
    const float* W2    = (const float*)d_in[5];
    const float* b2    = (const float*)d_in[6];
    float* out = (float*)d_out;

    const int N = in_sizes[0] / D;   // 100000
    const int E = in_sizes[1] / 2;   // 1000000

    char* w = (char*)d_ws;
    float* h    = (float*)w;  w += (size_t)N * D * 4;
    float* acc  = (float*)w;  w += (size_t)N * D * 4;
    int*   deg  = (int*)w;    w += (size_t)N * 4;
    float* dinv = (float*)w;  w += (size_t)N * 4;
    float* gsum = (float*)w;  w += (size_t)NG * D * 4;
    float* gcnt = (float*)w;  w += (size_t)NG * 4;

    // zero the accumulators we rely on (ws is poisoned, not re-zeroed by harness)
    hipMemsetAsync(deg, 0, (size_t)N * 4, stream);
    hipMemsetAsync(gsum, 0, (size_t)(NG * D + NG) * 4, stream);  // gsum + gcnt contiguous

    k_deg<<<(E + 255) / 256, 256, 0, stream>>>(ei + E, E, deg);
    k_xw1<<<(N + 3) / 4, 256, 0, stream>>>(x, W1, deg, N, h, dinv, acc);
    {
        long long threads = (long long)E * 64;
        int blocks = (int)((threads + 255) / 256);
        k_edge<<<blocks, 256, 0, stream>>>(ei, ei + E, E, h, dinv, acc);
    }
    {
        int waves = (N + NPW - 1) / NPW;
        long long threads = (long long)waves * 64;
        int blocks = (int)((threads + 255) / 256);
        k_pool<<<blocks, 256, 0, stream>>>(acc, b1, batch, N, gsum, gcnt);
    }
    k_head<<<1, 128, 0, stream>>>(gsum, gcnt, W2, b2, out);
}

// Round 3
// 290.860 us; speedup vs baseline: 3.0908x; 1.3590x over previous
//
#include <hip/hip_runtime.h>

#define D 64
#define NCLS 10
#define NG 128
#define NPW 64   // nodes per wave in k_pool

// ---- degree: deg[dst[e]] += 1 for each edge ----
__global__ void k_deg(const int* __restrict__ dst, int E, int* __restrict__ deg) {
    int e = blockIdx.x * blockDim.x + threadIdx.x;
    if (e < E) atomicAdd(&deg[dst[e]], 1);
}

// ---- h_scaled = (x @ W1) * dinv(row) ; dinv = rsqrt(deg+1) ----
__global__ void k_xw1(const float* __restrict__ x, const float* __restrict__ W1,
                      const int* __restrict__ deg, int N,
                      float* __restrict__ hs, float* __restrict__ dinv) {
    __shared__ float w[D * D];
    int tid = threadIdx.x;
    for (int i = tid; i < D * D; i += blockDim.x) w[i] = W1[i];
    __syncthreads();
    int row = blockIdx.x * 4 + (tid >> 6);
    int col = tid & 63;
    if (row >= N) return;
    const float* xr = x + (size_t)row * D;
    float s = 0.f;
#pragma unroll
    for (int k = 0; k < D; ++k) s += xr[k] * w[k * D + col];
    float d = rsqrtf((float)(deg[row] + 1));
    hs[(size_t)row * D + col] = s * d;
    if (col == 0) dinv[row] = d;
}

// ---- exclusive scan, 3 kernels: 1024 elems/block ----
__global__ void k_scan1(const int* __restrict__ deg, int N,
                        int* __restrict__ rowptr, int* __restrict__ bsum) {
    __shared__ int sd[256];
    int tid = threadIdx.x;
    int base = blockIdx.x * 1024 + tid * 4;
    int v0 = 0, v1 = 0, v2 = 0, v3 = 0;
    if (base + 0 < N) v0 = deg[base + 0];
    if (base + 1 < N) v1 = deg[base + 1];
    if (base + 2 < N) v2 = deg[base + 2];
    if (base + 3 < N) v3 = deg[base + 3];
    sd[tid] = v0 + v1 + v2 + v3;
    __syncthreads();
    for (int off = 1; off < 256; off <<= 1) {
        int tmp = (tid >= off) ? sd[tid - off] : 0;
        __syncthreads();
        sd[tid] += tmp;
        __syncthreads();
    }
    int excl = (tid == 0) ? 0 : sd[tid - 1];
    if (base + 0 < N) rowptr[base + 0] = excl;
    if (base + 1 < N) rowptr[base + 1] = excl + v0;
    if (base + 2 < N) rowptr[base + 2] = excl + v0 + v1;
    if (base + 3 < N) rowptr[base + 3] = excl + v0 + v1 + v2;
    if (tid == 255) bsum[blockIdx.x] = sd[255];
}

__global__ void k_scan2(int* __restrict__ bsum, int nb) {
    __shared__ int sd[128];
    int tid = threadIdx.x;
    int v = (tid < nb) ? bsum[tid] : 0;
    sd[tid] = v;
    __syncthreads();
    for (int off = 1; off < 128; off <<= 1) {
        int tmp = (tid >= off) ? sd[tid - off] : 0;
        __syncthreads();
        sd[tid] += tmp;
        __syncthreads();
    }
    if (tid < nb) bsum[tid] = (tid == 0) ? 0 : sd[tid - 1];
}

__global__ void k_scan3(int* __restrict__ rowptr, int* __restrict__ cursor,
                        const int* __restrict__ bsum, int N, int E) {
    int i = blockIdx.x * blockDim.x + threadIdx.x;
    if (i < N) {
        int v = rowptr[i] + bsum[i >> 10];
        rowptr[i] = v;
        cursor[i] = v;
    }
    if (i == 0) rowptr[N] = E;
}

// ---- bucket edges by dst (order within bucket arbitrary) ----
__global__ void k_scatter(const int* __restrict__ src, const int* __restrict__ dst, int E,
                          int* __restrict__ cursor, int* __restrict__ srcs) {
    int e = blockIdx.x * blockDim.x + threadIdx.x;
    if (e >= E) return;
    int t = dst[e];
    int pos = atomicAdd(&cursor[t], 1);
    srcs[pos] = src[e];
}

// ---- gather-aggregate: wave per dst node, lane = channel; no float atomics ----
__global__ void k_gather(const float* __restrict__ hs, const float* __restrict__ dinv,
                         const int* __restrict__ rowptr, const int* __restrict__ srcs,
                         const float* __restrict__ b1, int N, float* __restrict__ r) {
    int node = (blockIdx.x * blockDim.x + threadIdx.x) >> 6;
    int lane = threadIdx.x & 63;
    if (node >= N) return;
    int begin = rowptr[node];
    int end = rowptr[node + 1];
    float sum = hs[(size_t)node * D + lane];  // self-loop term (already *dinv[node])
    for (int k0 = begin; k0 < end; k0 += 64) {
        int kk = k0 + lane;
        int s_l = (kk < end) ? srcs[kk] : 0;
        int cnt = min(64, end - k0);
        int j = 0;
        for (; j + 1 < cnt; j += 2) {
            int s0 = __shfl(s_l, j);
            int s1 = __shfl(s_l, j + 1);
            float a0 = hs[(size_t)s0 * D + lane];
            float a1 = hs[(size_t)s1 * D + lane];
            sum += a0;
            sum += a1;
        }
        if (j < cnt) sum += hs[(size_t)__shfl(s_l, j) * D + lane];
    }
    float a = dinv[node] * sum + b1[lane];
    r[(size_t)node * D + lane] = fmaxf(a, 0.f);
}

// ---- mean-pool: sorted-batch run accumulation, flush on boundary ----
__global__ void k_pool(const float* __restrict__ r, const int* __restrict__ batch, int N,
                       float* __restrict__ gsum, float* __restrict__ gcnt) {
    int wid = (blockIdx.x * blockDim.x + threadIdx.x) >> 6;
    int lane = threadIdx.x & 63;
    int sub = lane >> 4;
    int c4  = lane & 15;
    int start = wid * NPW;
    if (start >= N) return;
    int end = min(start + NPW, N);
    const float4* r4 = (const float4*)r;
    float4 sum = make_float4(0.f, 0.f, 0.f, 0.f);
    float cnt = 0.f;
    int cur_g = -1;
    for (int i = start + sub; i < end; i += 4) {
        int g = batch[i];
        if (g != cur_g) {
            if (cur_g >= 0) {
                float* gs = &gsum[cur_g * D + c4 * 4];
                atomicAdd(gs + 0, sum.x);
                atomicAdd(gs + 1, sum.y);
                atomicAdd(gs + 2, sum.z);
                atomicAdd(gs + 3, sum.w);
                if (c4 == 0) atomicAdd(&gcnt[cur_g], cnt);
            }
            sum = make_float4(0.f, 0.f, 0.f, 0.f);
            cnt = 0.f;
            cur_g = g;
        }
        float4 v = r4[(size_t)i * (D / 4) + c4];
        sum.x += v.x; sum.y += v.y; sum.z += v.z; sum.w += v.w;
        cnt += 1.f;
    }
    if (cur_g >= 0) {
        float* gs = &gsum[cur_g * D + c4 * 4];
        atomicAdd(gs + 0, sum.x);
        atomicAdd(gs + 1, sum.y);
        atomicAdd(gs + 2, sum.z);
        atomicAdd(gs + 3, sum.w);
        if (c4 == 0) atomicAdd(&gcnt[cur_g], cnt);
    }
}

// ---- head: hG = gsum/cnt ; logits = hG@W2 + b2 ; log_softmax ----
__global__ void k_head(const float* __restrict__ gsum, const float* __restrict__ gcnt,
                       const float* __restrict__ W2, const float* __restrict__ b2,
                       float* __restrict__ out) {
    int g = threadIdx.x;
    if (g >= NG) return;
    float cnt = gcnt[g];
    cnt = cnt > 1.f ? cnt : 1.f;
    float inv = 1.f / cnt;
    float logits[NCLS];
#pragma unroll
    for (int c = 0; c < NCLS; ++c) logits[c] = b2[c];
    for (int k = 0; k < D; ++k) {
        float hk = gsum[g * D + k] * inv;
#pragma unroll
        for (int c = 0; c < NCLS; ++c) logits[c] += hk * W2[k * NCLS + c];
    }
    float m = logits[0];
#pragma unroll
    for (int c = 1; c < NCLS; ++c) m = fmaxf(m, logits[c]);
    float se = 0.f;
#pragma unroll
    for (int c = 0; c < NCLS; ++c) se += expf(logits[c] - m);
    float lse = m + logf(se);
#pragma unroll
    for (int c = 0; c < NCLS; ++c) out[g * NCLS + c] = logits[c] - lse;
}

static inline size_t pad256(size_t x) { return (x + 255) & ~(size_t)255; }

extern "C" void kernel_launch(void* const* d_in, const int* in_sizes, int n_in,
                              void* d_out, int out_size, void* d_ws, size_t ws_size,
                              hipStream_t stream) {
    const float* x     = (const float*)d_in[0];
    const int*   ei    = (const int*)d_in[1];   // [2, E]: src row then dst row
    const int*   batch = (const int*)d_in[2];
    const float* W1    = (const float*)d_in[3];
    const float* b1    = (const float*)d_in[4];
    const float* W2    = (const float*)d_in[5];
    const float* b2    = (const float*)d_in[6];
    float* out = (float*)d_out;

    const int N = in_sizes[0] / D;   // 100000
    const int E = in_sizes[1] / 2;   // 1000000

    char* w = (char*)d_ws;
    float* hs     = (float*)w;  w += pad256((size_t)N * D * 4);
    float* r      = (float*)w;  w += pad256((size_t)N * D * 4);
    int*   deg    = (int*)w;    w += pad256((size_t)N * 4);       // reused as cursor
    float* dinv   = (float*)w;  w += pad256((size_t)N * 4);
    int*   rowptr = (int*)w;    w += pad256((size_t)(N + 1) * 4);
    int*   srcs   = (int*)w;    w += pad256((size_t)E * 4);
    int*   bsum   = (int*)w;    w += pad256(128 * 4);
    float* gsum   = (float*)w;  w += pad256((size_t)NG * D * 4);
    float* gcnt   = (float*)w;  w += pad256((size_t)NG * 4);

    hipMemsetAsync(deg, 0, (size_t)N * 4, stream);
    hipMemsetAsync(gsum, 0, (size_t)NG * D * 4, stream);
    hipMemsetAsync(gcnt, 0, (size_t)NG * 4, stream);

    const int* e_src = ei;
    const int* e_dst = ei + E;

    k_deg<<<(E + 255) / 256, 256, 0, stream>>>(e_dst, E, deg);
    k_xw1<<<(N + 3) / 4, 256, 0, stream>>>(x, W1, deg, N, hs, dinv);

    int nb = (N + 1023) / 1024;   // 98 <= 128
    k_scan1<<<nb, 256, 0, stream>>>(deg, N, rowptr, bsum);
    k_scan2<<<1, 128, 0, stream>>>(bsum, nb);
    k_scan3<<<(N + 255) / 256, 256, 0, stream>>>(rowptr, deg /*cursor*/, bsum, N, E);

    k_scatter<<<(E + 255) / 256, 256, 0, stream>>>(e_src, e_dst, E, deg /*cursor*/, srcs);

    {
        long long threads = (long long)N * 64;
        int blocks = (int)((threads + 255) / 256);
        k_gather<<<blocks, 256, 0, stream>>>(hs, dinv, rowptr, srcs, b1, N, r);
    }
    {
        int waves = (N + NPW - 1) / NPW;
        long long threads = (long long)waves * 64;
        int blocks = (int)((threads + 255) / 256);
        k_pool<<<blocks, 256, 0, stream>>>(r, batch, N, gsum, gcnt);
    }
    k_head<<<1, 128, 0, stream>>>(gsum, gcnt, W2, b2, out);
}

// Round 4
// 235.825 us; speedup vs baseline: 3.8121x; 1.2334x over previous
//
#include <hip/hip_runtime.h>

#define D 64
#define NCLS 10
#define NG 128
#define NPW 64   // nodes per wave in k_pool

// ---- degree: deg[dst[e]] += 1 for each edge ----
__global__ void k_deg(const int* __restrict__ dst, int E, int* __restrict__ deg) {
    int e = blockIdx.x * blockDim.x + threadIdx.x;
    if (e < E) atomicAdd(&deg[dst[e]], 1);
}

// ---- h_scaled = (x @ W1) * dinv(row), LDS-tiled register-blocked GEMM ----
// Block: 256 threads -> 64 rows x 64 cols. Thread (rowg=tid>>4, col4=tid&15)
// computes 4 rows x float4 cols. All LDS reads broadcast/2-way (conflict-free).
__global__ __launch_bounds__(256) void k_xw1(const float* __restrict__ x,
                      const float* __restrict__ W1, const int* __restrict__ deg,
                      int N, float* __restrict__ hs, float* __restrict__ dinv) {
    __shared__ float wl[D * D];   // W1[k][c]
    __shared__ float xt[64 * D];  // x-tile, row-major [r][k]
    int tid = threadIdx.x;
    const float4* W4 = (const float4*)W1;
    float4* wl4 = (float4*)wl;
#pragma unroll
    for (int i = 0; i < 4; ++i) wl4[i * 256 + tid] = W4[i * 256 + tid];
    int row0 = blockIdx.x * 64;
    const float4* x4 = (const float4*)x;
    float4* xt4 = (float4*)xt;
#pragma unroll
    for (int i = 0; i < 4; ++i) {
        int flat = i * 256 + tid;            // float4 slot: row=flat>>4, c4=flat&15
        int row = row0 + (flat >> 4);
        float4 v = make_float4(0.f, 0.f, 0.f, 0.f);
        if (row < N) v = x4[(size_t)row * 16 + (flat & 15)];
        xt4[flat] = v;
    }
    __syncthreads();
    int col4 = tid & 15;
    int rowg = tid >> 4;
    float4 acc[4];
#pragma unroll
    for (int i = 0; i < 4; ++i) acc[i] = make_float4(0.f, 0.f, 0.f, 0.f);
#pragma unroll 8
    for (int k = 0; k < D; ++k) {
        float4 wv = *(const float4*)&wl[k * D + col4 * 4];
#pragma unroll
        for (int i = 0; i < 4; ++i) {
            float xv = xt[(rowg * 4 + i) * D + k];
            acc[i].x += xv * wv.x;
            acc[i].y += xv * wv.y;
            acc[i].z += xv * wv.z;
            acc[i].w += xv * wv.w;
        }
    }
#pragma unroll
    for (int i = 0; i < 4; ++i) {
        int row = row0 + rowg * 4 + i;
        if (row >= N) continue;
        float d = rsqrtf((float)(deg[row] + 1));
        float4 o = make_float4(acc[i].x * d, acc[i].y * d, acc[i].z * d, acc[i].w * d);
        ((float4*)hs)[(size_t)row * 16 + col4] = o;
        if (col4 == 0) dinv[row] = d;
    }
}

// ---- exclusive scan, 3 kernels: 1024 elems/block ----
__global__ void k_scan1(const int* __restrict__ deg, int N,
                        int* __restrict__ rowptr, int* __restrict__ bsum) {
    __shared__ int sd[256];
    int tid = threadIdx.x;
    int base = blockIdx.x * 1024 + tid * 4;
    int v0 = 0, v1 = 0, v2 = 0, v3 = 0;
    if (base + 0 < N) v0 = deg[base + 0];
    if (base + 1 < N) v1 = deg[base + 1];
    if (base + 2 < N) v2 = deg[base + 2];
    if (base + 3 < N) v3 = deg[base + 3];
    sd[tid] = v0 + v1 + v2 + v3;
    __syncthreads();
    for (int off = 1; off < 256; off <<= 1) {
        int tmp = (tid >= off) ? sd[tid - off] : 0;
        __syncthreads();
        sd[tid] += tmp;
        __syncthreads();
    }
    int excl = (tid == 0) ? 0 : sd[tid - 1];
    if (base + 0 < N) rowptr[base + 0] = excl;
    if (base + 1 < N) rowptr[base + 1] = excl + v0;
    if (base + 2 < N) rowptr[base + 2] = excl + v0 + v1;
    if (base + 3 < N) rowptr[base + 3] = excl + v0 + v1 + v2;
    if (tid == 255) bsum[blockIdx.x] = sd[255];
}

__global__ void k_scan2(int* __restrict__ bsum, int nb) {
    __shared__ int sd[128];
    int tid = threadIdx.x;
    int v = (tid < nb) ? bsum[tid] : 0;
    sd[tid] = v;
    __syncthreads();
    for (int off = 1; off < 128; off <<= 1) {
        int tmp = (tid >= off) ? sd[tid - off] : 0;
        __syncthreads();
        sd[tid] += tmp;
        __syncthreads();
    }
    if (tid < nb) bsum[tid] = (tid == 0) ? 0 : sd[tid - 1];
}

__global__ void k_scan3(int* __restrict__ rowptr, int* __restrict__ cursor,
                        const int* __restrict__ bsum, int N, int E) {
    int i = blockIdx.x * blockDim.x + threadIdx.x;
    if (i < N) {
        int v = rowptr[i] + bsum[i >> 10];
        rowptr[i] = v;
        cursor[i] = v;
    }
    if (i == 0) rowptr[N] = E;
}

// ---- bucket edges by dst (order within bucket arbitrary) ----
__global__ void k_scatter(const int* __restrict__ src, const int* __restrict__ dst, int E,
                          int* __restrict__ cursor, int* __restrict__ srcs) {
    int e = blockIdx.x * blockDim.x + threadIdx.x;
    if (e >= E) return;
    int t = dst[e];
    int pos = atomicAdd(&cursor[t], 1);
    srcs[pos] = src[e];
}

// ---- gather-aggregate: wave per dst node; 4 edges/iter, float4 per lane ----
// lane = (sub=lane>>4 edge slot, c4=lane&15 channel quad). Butterfly-reduce subs.
__global__ void k_gather(const float* __restrict__ hs, const float* __restrict__ dinv,
                         const int* __restrict__ rowptr, const int* __restrict__ srcs,
                         const float* __restrict__ b1, int N, float* __restrict__ r) {
    int node = (blockIdx.x * blockDim.x + threadIdx.x) >> 6;
    int lane = threadIdx.x & 63;
    if (node >= N) return;
    int begin = rowptr[node];
    int end = rowptr[node + 1];
    int c4 = lane & 15;
    int sub = lane >> 4;
    const float4* hs4 = (const float4*)hs;
    float4 sum = make_float4(0.f, 0.f, 0.f, 0.f);
    if (sub == 0) sum = hs4[(size_t)node * 16 + c4];  // self-loop (already *dinv[node])
    for (int k0 = begin; k0 < end; k0 += 64) {
        int kk = k0 + lane;
        int s_l = (kk < end) ? srcs[kk] : 0;
        int cnt = min(64, end - k0);
        for (int j4 = 0; j4 < cnt; j4 += 4) {
            int idx = j4 + sub;
            int s = __shfl(s_l, idx);
            if (idx < cnt) {
                float4 v = hs4[(size_t)s * 16 + c4];
                sum.x += v.x; sum.y += v.y; sum.z += v.z; sum.w += v.w;
            }
        }
    }
    // fold sub 0..3 partials (lanes c4, c4+16, c4+32, c4+48)
    sum.x += __shfl_xor(sum.x, 16); sum.y += __shfl_xor(sum.y, 16);
    sum.z += __shfl_xor(sum.z, 16); sum.w += __shfl_xor(sum.w, 16);
    sum.x += __shfl_xor(sum.x, 32); sum.y += __shfl_xor(sum.y, 32);
    sum.z += __shfl_xor(sum.z, 32); sum.w += __shfl_xor(sum.w, 32);
    if (sub == 0) {
        float d = dinv[node];
        float4 b = ((const float4*)b1)[c4];
        float4 o;
        o.x = fmaxf(sum.x * d + b.x, 0.f);
        o.y = fmaxf(sum.y * d + b.y, 0.f);
        o.z = fmaxf(sum.z * d + b.z, 0.f);
        o.w = fmaxf(sum.w * d + b.w, 0.f);
        ((float4*)r)[(size_t)node * 16 + c4] = o;
    }
}

// ---- mean-pool: sorted-batch run accumulation, flush on boundary ----
__global__ void k_pool(const float* __restrict__ r, const int* __restrict__ batch, int N,
                       float* __restrict__ gsum, float* __restrict__ gcnt) {
    int wid = (blockIdx.x * blockDim.x + threadIdx.x) >> 6;
    int lane = threadIdx.x & 63;
    int sub = lane >> 4;
    int c4  = lane & 15;
    int start = wid * NPW;
    if (start >= N) return;
    int end = min(start + NPW, N);
    const float4* r4 = (const float4*)r;
    float4 sum = make_float4(0.f, 0.f, 0.f, 0.f);
    float cnt = 0.f;
    int cur_g = -1;
    for (int i = start + sub; i < end; i += 4) {
        int g = batch[i];
        if (g != cur_g) {
            if (cur_g >= 0) {
                float* gs = &gsum[cur_g * D + c4 * 4];
                atomicAdd(gs + 0, sum.x);
                atomicAdd(gs + 1, sum.y);
                atomicAdd(gs + 2, sum.z);
                atomicAdd(gs + 3, sum.w);
                if (c4 == 0) atomicAdd(&gcnt[cur_g], cnt);
            }
            sum = make_float4(0.f, 0.f, 0.f, 0.f);
            cnt = 0.f;
            cur_g = g;
        }
        float4 v = r4[(size_t)i * (D / 4) + c4];
        sum.x += v.x; sum.y += v.y; sum.z += v.z; sum.w += v.w;
        cnt += 1.f;
    }
    if (cur_g >= 0) {
        float* gs = &gsum[cur_g * D + c4 * 4];
        atomicAdd(gs + 0, sum.x);
        atomicAdd(gs + 1, sum.y);
        atomicAdd(gs + 2, sum.z);
        atomicAdd(gs + 3, sum.w);
        if (c4 == 0) atomicAdd(&gcnt[cur_g], cnt);
    }
}

// ---- head: hG = gsum/cnt ; logits = hG@W2 + b2 ; log_softmax ----
__global__ void k_head(const float* __restrict__ gsum, const float* __restrict__ gcnt,
                       const float* __restrict__ W2, const float* __restrict__ b2,
                       float* __restrict__ out) {
    int g = threadIdx.x;
    if (g >= NG) return;
    float cnt = gcnt[g];
    cnt = cnt > 1.f ? cnt : 1.f;
    float inv = 1.f / cnt;
    float logits[NCLS];
#pragma unroll
    for (int c = 0; c < NCLS; ++c) logits[c] = b2[c];
    for (int k = 0; k < D; ++k) {
        float hk = gsum[g * D + k] * inv;
#pragma unroll
        for (int c = 0; c < NCLS; ++c) logits[c] += hk * W2[k * NCLS + c];
    }
    float m = logits[0];
#pragma unroll
    for (int c = 1; c < NCLS; ++c) m = fmaxf(m, logits[c]);
    float se = 0.f;
#pragma unroll
    for (int c = 0; c < NCLS; ++c) se += expf(logits[c] - m);
    float lse = m + logf(se);
#pragma unroll
    for (int c = 0; c < NCLS; ++c) out[g * NCLS + c] = logits[c] - lse;
}

static inline size_t pad256(size_t x) { return (x + 255) & ~(size_t)255; }

extern "C" void kernel_launch(void* const* d_in, const int* in_sizes, int n_in,
                              void* d_out, int out_size, void* d_ws, size_t ws_size,
                              hipStream_t stream) {
    const float* x     = (const float*)d_in[0];
    const int*   ei    = (const int*)d_in[1];   // [2, E]: src row then dst row
    const int*   batch = (const int*)d_in[2];
    const float* W1    = (const float*)d_in[3];
    const float* b1    = (const float*)d_in[4];
    const float* W2    = (const float*)d_in[5];
    const float* b2    = (const float*)d_in[6];
    float* out = (float*)d_out;

    const int N = in_sizes[0] / D;   // 100000
    const int E = in_sizes[1] / 2;   // 1000000

    char* w = (char*)d_ws;
    float* hs     = (float*)w;  w += pad256((size_t)N * D * 4);
    float* r      = (float*)w;  w += pad256((size_t)N * D * 4);
    int*   deg    = (int*)w;    w += pad256((size_t)N * 4);       // reused as cursor
    float* dinv   = (float*)w;  w += pad256((size_t)N * 4);
    int*   rowptr = (int*)w;    w += pad256((size_t)(N + 1) * 4);
    int*   srcs   = (int*)w;    w += pad256((size_t)E * 4);
    int*   bsum   = (int*)w;    w += pad256(128 * 4);
    float* gsum   = (float*)w;  w += pad256((size_t)NG * D * 4);
    float* gcnt   = (float*)w;  w += pad256((size_t)NG * 4);

    hipMemsetAsync(deg, 0, (size_t)N * 4, stream);
    hipMemsetAsync(gsum, 0, (size_t)NG * D * 4, stream);
    hipMemsetAsync(gcnt, 0, (size_t)NG * 4, stream);

    const int* e_src = ei;
    const int* e_dst = ei + E;

    k_deg<<<(E + 255) / 256, 256, 0, stream>>>(e_dst, E, deg);
    k_xw1<<<(N + 63) / 64, 256, 0, stream>>>(x, W1, deg, N, hs, dinv);

    int nb = (N + 1023) / 1024;   // 98 <= 128
    k_scan1<<<nb, 256, 0, stream>>>(deg, N, rowptr, bsum);
    k_scan2<<<1, 128, 0, stream>>>(bsum, nb);
    k_scan3<<<(N + 255) / 256, 256, 0, stream>>>(rowptr, deg /*cursor*/, bsum, N, E);

    k_scatter<<<(E + 255) / 256, 256, 0, stream>>>(e_src, e_dst, E, deg /*cursor*/, srcs);

    {
        long long threads = (long long)N * 64;
        int blocks = (int)((threads + 255) / 256);
        k_gather<<<blocks, 256, 0, stream>>>(hs, dinv, rowptr, srcs, b1, N, r);
    }
    {
        int waves = (N + NPW - 1) / NPW;
        long long threads = (long long)waves * 64;
        int blocks = (int)((threads + 255) / 256);
        k_pool<<<blocks, 256, 0, stream>>>(r, batch, N, gsum, gcnt);
    }
    k_head<<<1, 128, 0, stream>>>(gsum, gcnt, W2, b2, out);
}

// Round 5
// 216.647 us; speedup vs baseline: 4.1495x; 1.0885x over previous
//
#include <hip/hip_runtime.h>

#define D 64
#define NCLS 10
#define NG 128
#define NPW 64    // nodes per wave in k_pool
#define NBLK 64   // partition blocks for bucket build
#define MAXNB 512 // max coarse buckets (N/256)

// ---- degree: deg[dst[e]] += 1 for each edge ----
__global__ void k_deg(const int* __restrict__ dst, int E, int* __restrict__ deg) {
    int e = blockIdx.x * blockDim.x + threadIdx.x;
    if (e < E) atomicAdd(&deg[dst[e]], 1);
}

// ---- h_scaled = (x @ W1) * dinv(row), LDS-tiled register-blocked GEMM ----
__global__ __launch_bounds__(256) void k_xw1(const float* __restrict__ x,
                      const float* __restrict__ W1, const int* __restrict__ deg,
                      int N, float* __restrict__ hs, float* __restrict__ dinv) {
    __shared__ float wl[D * D];   // W1[k][c]
    __shared__ float xt[64 * D];  // x-tile, row-major [r][k]
    int tid = threadIdx.x;
    const float4* W4 = (const float4*)W1;
    float4* wl4 = (float4*)wl;
#pragma unroll
    for (int i = 0; i < 4; ++i) wl4[i * 256 + tid] = W4[i * 256 + tid];
    int row0 = blockIdx.x * 64;
    const float4* x4 = (const float4*)x;
    float4* xt4 = (float4*)xt;
#pragma unroll
    for (int i = 0; i < 4; ++i) {
        int flat = i * 256 + tid;
        int row = row0 + (flat >> 4);
        float4 v = make_float4(0.f, 0.f, 0.f, 0.f);
        if (row < N) v = x4[(size_t)row * 16 + (flat & 15)];
        xt4[flat] = v;
    }
    __syncthreads();
    int col4 = tid & 15;
    int rowg = tid >> 4;
    float4 acc[4];
#pragma unroll
    for (int i = 0; i < 4; ++i) acc[i] = make_float4(0.f, 0.f, 0.f, 0.f);
#pragma unroll 8
    for (int k = 0; k < D; ++k) {
        float4 wv = *(const float4*)&wl[k * D + col4 * 4];
#pragma unroll
        for (int i = 0; i < 4; ++i) {
            float xv = xt[(rowg * 4 + i) * D + k];
            acc[i].x += xv * wv.x;
            acc[i].y += xv * wv.y;
            acc[i].z += xv * wv.z;
            acc[i].w += xv * wv.w;
        }
    }
#pragma unroll
    for (int i = 0; i < 4; ++i) {
        int row = row0 + rowg * 4 + i;
        if (row >= N) continue;
        float d = rsqrtf((float)(deg[row] + 1));
        float4 o = make_float4(acc[i].x * d, acc[i].y * d, acc[i].z * d, acc[i].w * d);
        ((float4*)hs)[(size_t)row * 16 + col4] = o;
        if (col4 == 0) dinv[row] = d;
    }
}

// ---- exclusive scan of deg -> rowptr, 3 kernels ----
__global__ void k_scan1(const int* __restrict__ deg, int N,
                        int* __restrict__ rowptr, int* __restrict__ bsum) {
    __shared__ int sd[256];
    int tid = threadIdx.x;
    int base = blockIdx.x * 1024 + tid * 4;
    int v0 = 0, v1 = 0, v2 = 0, v3 = 0;
    if (base + 0 < N) v0 = deg[base + 0];
    if (base + 1 < N) v1 = deg[base + 1];
    if (base + 2 < N) v2 = deg[base + 2];
    if (base + 3 < N) v3 = deg[base + 3];
    sd[tid] = v0 + v1 + v2 + v3;
    __syncthreads();
    for (int off = 1; off < 256; off <<= 1) {
        int tmp = (tid >= off) ? sd[tid - off] : 0;
        __syncthreads();
        sd[tid] += tmp;
        __syncthreads();
    }
    int excl = (tid == 0) ? 0 : sd[tid - 1];
    if (base + 0 < N) rowptr[base + 0] = excl;
    if (base + 1 < N) rowptr[base + 1] = excl + v0;
    if (base + 2 < N) rowptr[base + 2] = excl + v0 + v1;
    if (base + 3 < N) rowptr[base + 3] = excl + v0 + v1 + v2;
    if (tid == 255) bsum[blockIdx.x] = sd[255];
}

__global__ void k_scan2(int* __restrict__ bsum, int nb) {
    __shared__ int sd[128];
    int tid = threadIdx.x;
    int v = (tid < nb) ? bsum[tid] : 0;
    sd[tid] = v;
    __syncthreads();
    for (int off = 1; off < 128; off <<= 1) {
        int tmp = (tid >= off) ? sd[tid - off] : 0;
        __syncthreads();
        sd[tid] += tmp;
        __syncthreads();
    }
    if (tid < nb) bsum[tid] = (tid == 0) ? 0 : sd[tid - 1];
}

__global__ void k_scan3(int* __restrict__ rowptr, const int* __restrict__ bsum,
                        int N, int E) {
    int i = blockIdx.x * blockDim.x + threadIdx.x;
    if (i < N) rowptr[i] += bsum[i >> 10];
    if (i == 0) rowptr[N] = E;
}

// ---- bucket build pass 1: per-block histogram of dst>>8 ----
__global__ __launch_bounds__(256) void k_bcount(const int* __restrict__ dst, int E,
                                                int NB, int* __restrict__ blkCount) {
    __shared__ int cnt[MAXNB];
    int tid = threadIdx.x;
    int blk = blockIdx.x;
    for (int b = tid; b < NB; b += 256) cnt[b] = 0;
    __syncthreads();
    int ch = (E + NBLK - 1) / NBLK;
    int beg = blk * ch, end = min(beg + ch, E);
    for (int i = beg + tid; i < end; i += 256) atomicAdd(&cnt[dst[i] >> 8], 1);
    __syncthreads();
    for (int b = tid; b < NB; b += 256) blkCount[b * NBLK + blk] = cnt[b];
}

// ---- bucket build pass 2: totals -> exclusive bases, per-(bucket,block) bases ----
__global__ __launch_bounds__(512) void k_bbase(int* __restrict__ blkCount, int NB, int E,
                                               int* __restrict__ bucketBase) {
    __shared__ int sd[512];
    int tid = threadIdx.x;
    int4 c[NBLK / 4];
    int tot = 0;
    if (tid < NB) {
        const int4* p = (const int4*)&blkCount[tid * NBLK];
#pragma unroll
        for (int j = 0; j < NBLK / 4; ++j) {
            c[j] = p[j];
            tot += c[j].x + c[j].y + c[j].z + c[j].w;
        }
    }
    sd[tid] = (tid < NB) ? tot : 0;
    __syncthreads();
    for (int off = 1; off < 512; off <<= 1) {
        int tmp = (tid >= off) ? sd[tid - off] : 0;
        __syncthreads();
        sd[tid] += tmp;
        __syncthreads();
    }
    if (tid < NB) {
        int run = (tid == 0) ? 0 : sd[tid - 1];
        bucketBase[tid] = run;
        int4* p = (int4*)&blkCount[tid * NBLK];
#pragma unroll
        for (int j = 0; j < NBLK / 4; ++j) {
            int t0 = c[j].x; c[j].x = run; run += t0;
            int t1 = c[j].y; c[j].y = run; run += t1;
            int t2 = c[j].z; c[j].z = run; run += t2;
            int t3 = c[j].w; c[j].w = run; run += t3;
            p[j] = c[j];
        }
    }
    if (tid == 0) bucketBase[NB] = E;
}

// ---- bucket build pass 3: place packed (src<<8)|dstLocal grouped by bucket ----
__global__ __launch_bounds__(256) void k_bplace(const int* __restrict__ src,
                                                const int* __restrict__ dst, int E,
                                                int NB, const int* __restrict__ blkCount,
                                                int* __restrict__ e2p) {
    __shared__ int cur[MAXNB];
    int tid = threadIdx.x;
    int blk = blockIdx.x;
    for (int b = tid; b < NB; b += 256) cur[b] = blkCount[b * NBLK + blk];
    __syncthreads();
    int ch = (E + NBLK - 1) / NBLK;
    int beg = blk * ch, end = min(beg + ch, E);
    for (int i = beg + tid; i < end; i += 256) {
        int s = src[i], t = dst[i];
        int pos = atomicAdd(&cur[t >> 8], 1);
        e2p[pos] = (s << 8) | (t & 255);
    }
}

// ---- CSR finalize: within-bucket scatter to srcs (one block per bucket) ----
__global__ __launch_bounds__(256) void k_csr(const int* __restrict__ e2p,
                                             const int* __restrict__ bucketBase,
                                             const int* __restrict__ rowptr, int N,
                                             int* __restrict__ srcs) {
    __shared__ int cur[256];
    int tid = threadIdx.x;
    int node0 = blockIdx.x << 8;
    if (node0 + tid < N) cur[tid] = rowptr[node0 + tid];
    __syncthreads();
    int beg = bucketBase[blockIdx.x];
    int end = bucketBase[blockIdx.x + 1];
    for (int i = beg + tid; i < end; i += 256) {
        int p = e2p[i];
        int pos = atomicAdd(&cur[p & 255], 1);
        srcs[pos] = p >> 8;
    }
}

// ---- gather-aggregate: wave per dst node; 4 edges/iter, float4 per lane ----
__global__ void k_gather(const float* __restrict__ hs, const float* __restrict__ dinv,
                         const int* __restrict__ rowptr, const int* __restrict__ srcs,
                         const float* __restrict__ b1, int N, float* __restrict__ r) {
    int node = (blockIdx.x * blockDim.x + threadIdx.x) >> 6;
    int lane = threadIdx.x & 63;
    if (node >= N) return;
    int begin = rowptr[node];
    int end = rowptr[node + 1];
    int c4 = lane & 15;
    int sub = lane >> 4;
    const float4* hs4 = (const float4*)hs;
    float4 sum = make_float4(0.f, 0.f, 0.f, 0.f);
    if (sub == 0) sum = hs4[(size_t)node * 16 + c4];  // self-loop
    for (int k0 = begin; k0 < end; k0 += 64) {
        int kk = k0 + lane;
        int s_l = (kk < end) ? srcs[kk] : 0;
        int cnt = min(64, end - k0);
        for (int j4 = 0; j4 < cnt; j4 += 4) {
            int idx = j4 + sub;
            int s = __shfl(s_l, idx);
            if (idx < cnt) {
                float4 v = hs4[(size_t)s * 16 + c4];
                sum.x += v.x; sum.y += v.y; sum.z += v.z; sum.w += v.w;
            }
        }
    }
    sum.x += __shfl_xor(sum.x, 16); sum.y += __shfl_xor(sum.y, 16);
    sum.z += __shfl_xor(sum.z, 16); sum.w += __shfl_xor(sum.w, 16);
    sum.x += __shfl_xor(sum.x, 32); sum.y += __shfl_xor(sum.y, 32);
    sum.z += __shfl_xor(sum.z, 32); sum.w += __shfl_xor(sum.w, 32);
    if (sub == 0) {
        float d = dinv[node];
        float4 b = ((const float4*)b1)[c4];
        float4 o;
        o.x = fmaxf(sum.x * d + b.x, 0.f);
        o.y = fmaxf(sum.y * d + b.y, 0.f);
        o.z = fmaxf(sum.z * d + b.z, 0.f);
        o.w = fmaxf(sum.w * d + b.w, 0.f);
        ((float4*)r)[(size_t)node * 16 + c4] = o;
    }
}

// ---- mean-pool: sorted-batch run accumulation, flush on boundary ----
__global__ void k_pool(const float* __restrict__ r, const int* __restrict__ batch, int N,
                       float* __restrict__ gsum, float* __restrict__ gcnt) {
    int wid = (blockIdx.x * blockDim.x + threadIdx.x) >> 6;
    int lane = threadIdx.x & 63;
    int sub = lane >> 4;
    int c4  = lane & 15;
    int start = wid * NPW;
    if (start >= N) return;
    int end = min(start + NPW, N);
    const float4* r4 = (const float4*)r;
    float4 sum = make_float4(0.f, 0.f, 0.f, 0.f);
    float cnt = 0.f;
    int cur_g = -1;
    for (int i = start + sub; i < end; i += 4) {
        int g = batch[i];
        if (g != cur_g) {
            if (cur_g >= 0) {
                float* gs = &gsum[cur_g * D + c4 * 4];
                atomicAdd(gs + 0, sum.x);
                atomicAdd(gs + 1, sum.y);
                atomicAdd(gs + 2, sum.z);
                atomicAdd(gs + 3, sum.w);
                if (c4 == 0) atomicAdd(&gcnt[cur_g], cnt);
            }
            sum = make_float4(0.f, 0.f, 0.f, 0.f);
            cnt = 0.f;
            cur_g = g;
        }
        float4 v = r4[(size_t)i * (D / 4) + c4];
        sum.x += v.x; sum.y += v.y; sum.z += v.z; sum.w += v.w;
        cnt += 1.f;
    }
    if (cur_g >= 0) {
        float* gs = &gsum[cur_g * D + c4 * 4];
        atomicAdd(gs + 0, sum.x);
        atomicAdd(gs + 1, sum.y);
        atomicAdd(gs + 2, sum.z);
        atomicAdd(gs + 3, sum.w);
        if (c4 == 0) atomicAdd(&gcnt[cur_g], cnt);
    }
}

// ---- head ----
__global__ void k_head(const float* __restrict__ gsum, const float* __restrict__ gcnt,
                       const float* __restrict__ W2, const float* __restrict__ b2,
                       float* __restrict__ out) {
    int g = threadIdx.x;
    if (g >= NG) return;
    float cnt = gcnt[g];
    cnt = cnt > 1.f ? cnt : 1.f;
    float inv = 1.f / cnt;
    float logits[NCLS];
#pragma unroll
    for (int c = 0; c < NCLS; ++c) logits[c] = b2[c];
    for (int k = 0; k < D; ++k) {
        float hk = gsum[g * D + k] * inv;
#pragma unroll
        for (int c = 0; c < NCLS; ++c) logits[c] += hk * W2[k * NCLS + c];
    }
    float m = logits[0];
#pragma unroll
    for (int c = 1; c < NCLS; ++c) m = fmaxf(m, logits[c]);
    float se = 0.f;
#pragma unroll
    for (int c = 0; c < NCLS; ++c) se += expf(logits[c] - m);
    float lse = m + logf(se);
#pragma unroll
    for (int c = 0; c < NCLS; ++c) out[g * NCLS + c] = logits[c] - lse;
}

static inline size_t pad256(size_t x) { return (x + 255) & ~(size_t)255; }

extern "C" void kernel_launch(void* const* d_in, const int* in_sizes, int n_in,
                              void* d_out, int out_size, void* d_ws, size_t ws_size,
                              hipStream_t stream) {
    const float* x     = (const float*)d_in[0];
    const int*   ei    = (const int*)d_in[1];   // [2, E]: src row then dst row
    const int*   batch = (const int*)d_in[2];
    const float* W1    = (const float*)d_in[3];
    const float* b1    = (const float*)d_in[4];
    const float* W2    = (const float*)d_in[5];
    const float* b2    = (const float*)d_in[6];
    float* out = (float*)d_out;

    const int N = in_sizes[0] / D;   // 100000
    const int E = in_sizes[1] / 2;   // 1000000
    const int NB = (N + 255) >> 8;   // 391 coarse buckets

    char* w = (char*)d_ws;
    float* hs         = (float*)w;  w += pad256((size_t)N * D * 4);
    float* r          = (float*)w;  w += pad256((size_t)N * D * 4);
    int*   deg        = (int*)w;    w += pad256((size_t)N * 4);
    float* dinv       = (float*)w;  w += pad256((size_t)N * 4);
    int*   rowptr     = (int*)w;    w += pad256((size_t)(N + 1) * 4);
    int*   srcs       = (int*)w;    w += pad256((size_t)E * 4);
    int*   e2p        = (int*)w;    w += pad256((size_t)E * 4);
    int*   blkCount   = (int*)w;    w += pad256((size_t)MAXNB * NBLK * 4);
    int*   bucketBase = (int*)w;    w += pad256((size_t)(MAXNB + 1) * 4);
    int*   bsum       = (int*)w;    w += pad256(128 * 4);
    float* gsum       = (float*)w;  w += pad256((size_t)NG * D * 4);
    float* gcnt       = (float*)w;  w += pad256((size_t)NG * 4);

    hipMemsetAsync(deg, 0, (size_t)N * 4, stream);
    hipMemsetAsync(gsum, 0, (size_t)NG * D * 4, stream);
    hipMemsetAsync(gcnt, 0, (size_t)NG * 4, stream);

    const int* e_src = ei;
    const int* e_dst = ei + E;

    k_deg<<<(E + 255) / 256, 256, 0, stream>>>(e_dst, E, deg);
    k_xw1<<<(N + 63) / 64, 256, 0, stream>>>(x, W1, deg, N, hs, dinv);

    int nb = (N + 1023) / 1024;
    k_scan1<<<nb, 256, 0, stream>>>(deg, N, rowptr, bsum);
    k_scan2<<<1, 128, 0, stream>>>(bsum, nb);
    k_scan3<<<(N + 255) / 256, 256, 0, stream>>>(rowptr, bsum, N, E);

    k_bcount<<<NBLK, 256, 0, stream>>>(e_dst, E, NB, blkCount);
    k_bbase<<<1, 512, 0, stream>>>(blkCount, NB, E, bucketBase);
    k_bplace<<<NBLK, 256, 0, stream>>>(e_src, e_dst, E, NB, blkCount, e2p);
    k_csr<<<NB, 256, 0, stream>>>(e2p, bucketBase, rowptr, N, srcs);

    {
        long long threads = (long long)N * 64;
        int blocks = (int)((threads + 255) / 256);
        k_gather<<<blocks, 256, 0, stream>>>(hs, dinv, rowptr, srcs, b1, N, r);
    }
    {
        int waves = (N + NPW - 1) / NPW;
        long long threads = (long long)waves * 64;
        int blocks = (int)((threads + 255) / 256);
        k_pool<<<blocks, 256, 0, stream>>>(r, batch, N, gsum, gcnt);
    }
    k_head<<<1, 128, 0, stream>>>(gsum, gcnt, W2, b2, out);
}

// Round 6
// 166.182 us; speedup vs baseline: 5.4096x; 1.3037x over previous
//
#include <hip/hip_runtime.h>

#define D 64
#define NCLS 10
#define NG 128
#define NPW 64    // nodes per wave in k_pool
#define NBLK 64   // partition blocks for bucket build
#define MAXNB 512 // max coarse buckets (N/256)

// bf16 helpers (RNE encode, cheap decode)
__device__ __forceinline__ unsigned short f2bf(float v) {
    unsigned b = __float_as_uint(v);
    b += 0x7fff + ((b >> 16) & 1);
    return (unsigned short)(b >> 16);
}
__device__ __forceinline__ float bf2f(unsigned short h) {
    return __uint_as_float(((unsigned)h) << 16);
}

// ---- h_scaled = (x @ W1) * dinv(row) -> bf16, LDS-tiled register-blocked GEMM ----
__global__ __launch_bounds__(256) void k_xw1(const float* __restrict__ x,
                      const float* __restrict__ W1, const float* __restrict__ dinv,
                      int N, ushort4* __restrict__ hs4) {
    __shared__ float wl[D * D];   // W1[k][c]
    __shared__ float xt[64 * D];  // x-tile, row-major [r][k]
    int tid = threadIdx.x;
    const float4* W4 = (const float4*)W1;
    float4* wl4 = (float4*)wl;
#pragma unroll
    for (int i = 0; i < 4; ++i) wl4[i * 256 + tid] = W4[i * 256 + tid];
    int row0 = blockIdx.x * 64;
    const float4* x4 = (const float4*)x;
    float4* xt4 = (float4*)xt;
#pragma unroll
    for (int i = 0; i < 4; ++i) {
        int flat = i * 256 + tid;
        int row = row0 + (flat >> 4);
        float4 v = make_float4(0.f, 0.f, 0.f, 0.f);
        if (row < N) v = x4[(size_t)row * 16 + (flat & 15)];
        xt4[flat] = v;
    }
    __syncthreads();
    int col4 = tid & 15;
    int rowg = tid >> 4;
    float4 acc[4];
#pragma unroll
    for (int i = 0; i < 4; ++i) acc[i] = make_float4(0.f, 0.f, 0.f, 0.f);
#pragma unroll 8
    for (int k = 0; k < D; ++k) {
        float4 wv = *(const float4*)&wl[k * D + col4 * 4];
#pragma unroll
        for (int i = 0; i < 4; ++i) {
            float xv = xt[(rowg * 4 + i) * D + k];
            acc[i].x += xv * wv.x;
            acc[i].y += xv * wv.y;
            acc[i].z += xv * wv.z;
            acc[i].w += xv * wv.w;
        }
    }
#pragma unroll
    for (int i = 0; i < 4; ++i) {
        int row = row0 + rowg * 4 + i;
        if (row >= N) continue;
        float d = dinv[row];
        ushort4 o;
        o.x = f2bf(acc[i].x * d);
        o.y = f2bf(acc[i].y * d);
        o.z = f2bf(acc[i].z * d);
        o.w = f2bf(acc[i].w * d);
        hs4[(size_t)row * 16 + col4] = o;
    }
}

// ---- bucket build pass 1: per-block histogram of dst>>8 ----
__global__ __launch_bounds__(256) void k_bcount(const int* __restrict__ dst, int E,
                                                int NB, int* __restrict__ blkCount) {
    __shared__ int cnt[MAXNB];
    int tid = threadIdx.x;
    int blk = blockIdx.x;
    for (int b = tid; b < NB; b += 256) cnt[b] = 0;
    __syncthreads();
    int ch = (E + NBLK - 1) / NBLK;
    int beg = blk * ch, end = min(beg + ch, E);
    for (int i = beg + tid; i < end; i += 256) atomicAdd(&cnt[dst[i] >> 8], 1);
    __syncthreads();
    for (int b = tid; b < NB; b += 256) blkCount[b * NBLK + blk] = cnt[b];
}

// ---- bucket build pass 2: totals -> exclusive bases, per-(bucket,block) bases ----
__global__ __launch_bounds__(512) void k_bbase(int* __restrict__ blkCount, int NB, int E,
                                               int* __restrict__ bucketBase) {
    __shared__ int sd[512];
    int tid = threadIdx.x;
    int4 c[NBLK / 4];
    int tot = 0;
    if (tid < NB) {
        const int4* p = (const int4*)&blkCount[tid * NBLK];
#pragma unroll
        for (int j = 0; j < NBLK / 4; ++j) {
            c[j] = p[j];
            tot += c[j].x + c[j].y + c[j].z + c[j].w;
        }
    }
    sd[tid] = (tid < NB) ? tot : 0;
    __syncthreads();
    for (int off = 1; off < 512; off <<= 1) {
        int tmp = (tid >= off) ? sd[tid - off] : 0;
        __syncthreads();
        sd[tid] += tmp;
        __syncthreads();
    }
    if (tid < NB) {
        int run = (tid == 0) ? 0 : sd[tid - 1];
        bucketBase[tid] = run;
        int4* p = (int4*)&blkCount[tid * NBLK];
#pragma unroll
        for (int j = 0; j < NBLK / 4; ++j) {
            int t0 = c[j].x; c[j].x = run; run += t0;
            int t1 = c[j].y; c[j].y = run; run += t1;
            int t2 = c[j].z; c[j].z = run; run += t2;
            int t3 = c[j].w; c[j].w = run; run += t3;
            p[j] = c[j];
        }
    }
    if (tid == 0) bucketBase[NB] = E;
}

// ---- bucket build pass 3: place packed (src<<8)|dstLocal grouped by bucket ----
__global__ __launch_bounds__(256) void k_bplace(const int* __restrict__ src,
                                                const int* __restrict__ dst, int E,
                                                int NB, const int* __restrict__ blkCount,
                                                int* __restrict__ e2p) {
    __shared__ int cur[MAXNB];
    int tid = threadIdx.x;
    int blk = blockIdx.x;
    for (int b = tid; b < NB; b += 256) cur[b] = blkCount[b * NBLK + blk];
    __syncthreads();
    int ch = (E + NBLK - 1) / NBLK;
    int beg = blk * ch, end = min(beg + ch, E);
    for (int i = beg + tid; i < end; i += 256) {
        int s = src[i], t = dst[i];
        int pos = atomicAdd(&cur[t >> 8], 1);
        e2p[pos] = (s << 8) | (t & 255);
    }
}

// ---- fused CSR finalize: per-bucket histogram+scan -> rowptr & dinv, scatter srcs ----
__global__ __launch_bounds__(256) void k_csrdeg(const int* __restrict__ e2p,
                                                const int* __restrict__ bucketBase,
                                                int N, int E,
                                                int* __restrict__ rowptr,
                                                float* __restrict__ dinv,
                                                int* __restrict__ srcs) {
    __shared__ int cnt[256];
    __shared__ int sd[256];
    __shared__ int cur[256];
    int tid = threadIdx.x;
    int node0 = blockIdx.x << 8;
    int bb = bucketBase[blockIdx.x];
    int end = bucketBase[blockIdx.x + 1];
    cnt[tid] = 0;
    __syncthreads();
    for (int i = bb + tid; i < end; i += 256) atomicAdd(&cnt[e2p[i] & 255], 1);
    __syncthreads();
    sd[tid] = cnt[tid];
    __syncthreads();
    for (int off = 1; off < 256; off <<= 1) {
        int tmp = (tid >= off) ? sd[tid - off] : 0;
        __syncthreads();
        sd[tid] += tmp;
        __syncthreads();
    }
    int excl = (tid == 0) ? 0 : sd[tid - 1];
    int node = node0 + tid;
    if (node < N) {
        rowptr[node] = bb + excl;
        dinv[node] = rsqrtf((float)(cnt[tid] + 1));
    }
    cur[tid] = bb + excl;
    if (blockIdx.x == 0 && tid == 0) rowptr[N] = E;
    __syncthreads();
    for (int i = bb + tid; i < end; i += 256) {
        int p = e2p[i];
        int pos = atomicAdd(&cur[p & 255], 1);
        srcs[pos] = p >> 8;
    }
}

// ---- gather-aggregate: wave per dst node; 4 edges/iter, bf16 ushort4 per lane ----
__global__ void k_gather(const ushort4* __restrict__ hs4, const float* __restrict__ dinv,
                         const int* __restrict__ rowptr, const int* __restrict__ srcs,
                         const float* __restrict__ b1, int N, ushort4* __restrict__ r4) {
    int node = (blockIdx.x * blockDim.x + threadIdx.x) >> 6;
    int lane = threadIdx.x & 63;
    if (node >= N) return;
    int begin = rowptr[node];
    int end = rowptr[node + 1];
    int c4 = lane & 15;
    int sub = lane >> 4;
    float4 sum = make_float4(0.f, 0.f, 0.f, 0.f);
    if (sub == 0) {  // self-loop (already *dinv[node])
        ushort4 u = hs4[(size_t)node * 16 + c4];
        sum.x = bf2f(u.x); sum.y = bf2f(u.y); sum.z = bf2f(u.z); sum.w = bf2f(u.w);
    }
    for (int k0 = begin; k0 < end; k0 += 64) {
        int kk = k0 + lane;
        int s_l = (kk < end) ? srcs[kk] : 0;
        int cnt = min(64, end - k0);
        for (int j4 = 0; j4 < cnt; j4 += 4) {
            int idx = j4 + sub;
            int s = __shfl(s_l, idx);
            if (idx < cnt) {
                ushort4 u = hs4[(size_t)s * 16 + c4];
                sum.x += bf2f(u.x);
                sum.y += bf2f(u.y);
                sum.z += bf2f(u.z);
                sum.w += bf2f(u.w);
            }
        }
    }
    sum.x += __shfl_xor(sum.x, 16); sum.y += __shfl_xor(sum.y, 16);
    sum.z += __shfl_xor(sum.z, 16); sum.w += __shfl_xor(sum.w, 16);
    sum.x += __shfl_xor(sum.x, 32); sum.y += __shfl_xor(sum.y, 32);
    sum.z += __shfl_xor(sum.z, 32); sum.w += __shfl_xor(sum.w, 32);
    if (sub == 0) {
        float d = dinv[node];
        float4 b = ((const float4*)b1)[c4];
        ushort4 o;
        o.x = f2bf(fmaxf(sum.x * d + b.x, 0.f));
        o.y = f2bf(fmaxf(sum.y * d + b.y, 0.f));
        o.z = f2bf(fmaxf(sum.z * d + b.z, 0.f));
        o.w = f2bf(fmaxf(sum.w * d + b.w, 0.f));
        r4[(size_t)node * 16 + c4] = o;
    }
}

// ---- mean-pool: sorted-batch run accumulation (bf16 in, fp32 accum) ----
__global__ void k_pool(const ushort4* __restrict__ r4, const int* __restrict__ batch,
                       int N, float* __restrict__ gsum, float* __restrict__ gcnt) {
    int wid = (blockIdx.x * blockDim.x + threadIdx.x) >> 6;
    int lane = threadIdx.x & 63;
    int sub = lane >> 4;
    int c4  = lane & 15;
    int start = wid * NPW;
    if (start >= N) return;
    int end = min(start + NPW, N);
    float4 sum = make_float4(0.f, 0.f, 0.f, 0.f);
    float cnt = 0.f;
    int cur_g = -1;
    for (int i = start + sub; i < end; i += 4) {
        int g = batch[i];
        if (g != cur_g) {
            if (cur_g >= 0) {
                float* gs = &gsum[cur_g * D + c4 * 4];
                atomicAdd(gs + 0, sum.x);
                atomicAdd(gs + 1, sum.y);
                atomicAdd(gs + 2, sum.z);
                atomicAdd(gs + 3, sum.w);
                if (c4 == 0) atomicAdd(&gcnt[cur_g], cnt);
            }
            sum = make_float4(0.f, 0.f, 0.f, 0.f);
            cnt = 0.f;
            cur_g = g;
        }
        ushort4 u = r4[(size_t)i * 16 + c4];
        sum.x += bf2f(u.x); sum.y += bf2f(u.y);
        sum.z += bf2f(u.z); sum.w += bf2f(u.w);
        cnt += 1.f;
    }
    if (cur_g >= 0) {
        float* gs = &gsum[cur_g * D + c4 * 4];
        atomicAdd(gs + 0, sum.x);
        atomicAdd(gs + 1, sum.y);
        atomicAdd(gs + 2, sum.z);
        atomicAdd(gs + 3, sum.w);
        if (c4 == 0) atomicAdd(&gcnt[cur_g], cnt);
    }
}

// ---- head ----
__global__ void k_head(const float* __restrict__ gsum, const float* __restrict__ gcnt,
                       const float* __restrict__ W2, const float* __restrict__ b2,
                       float* __restrict__ out) {
    int g = threadIdx.x;
    if (g >= NG) return;
    float cnt = gcnt[g];
    cnt = cnt > 1.f ? cnt : 1.f;
    float inv = 1.f / cnt;
    float logits[NCLS];
#pragma unroll
    for (int c = 0; c < NCLS; ++c) logits[c] = b2[c];
    for (int k = 0; k < D; ++k) {
        float hk = gsum[g * D + k] * inv;
#pragma unroll
        for (int c = 0; c < NCLS; ++c) logits[c] += hk * W2[k * NCLS + c];
    }
    float m = logits[0];
#pragma unroll
    for (int c = 1; c < NCLS; ++c) m = fmaxf(m, logits[c]);
    float se = 0.f;
#pragma unroll
    for (int c = 0; c < NCLS; ++c) se += expf(logits[c] - m);
    float lse = m + logf(se);
#pragma unroll
    for (int c = 0; c < NCLS; ++c) out[g * NCLS + c] = logits[c] - lse;
}

static inline size_t pad256(size_t x) { return (x + 255) & ~(size_t)255; }

extern "C" void kernel_launch(void* const* d_in, const int* in_sizes, int n_in,
                              void* d_out, int out_size, void* d_ws, size_t ws_size,
                              hipStream_t stream) {
    const float* x     = (const float*)d_in[0];
    const int*   ei    = (const int*)d_in[1];   // [2, E]: src row then dst row
    const int*   batch = (const int*)d_in[2];
    const float* W1    = (const float*)d_in[3];
    const float* b1    = (const float*)d_in[4];
    const float* W2    = (const float*)d_in[5];
    const float* b2    = (const float*)d_in[6];
    float* out = (float*)d_out;

    const int N = in_sizes[0] / D;   // 100000
    const int E = in_sizes[1] / 2;   // 1000000
    const int NB = (N + 255) >> 8;   // 391 coarse buckets

    char* w = (char*)d_ws;
    ushort4* hs4      = (ushort4*)w; w += pad256((size_t)N * D * 2);
    ushort4* r4       = (ushort4*)w; w += pad256((size_t)N * D * 2);
    float* dinv       = (float*)w;  w += pad256((size_t)N * 4);
    int*   rowptr     = (int*)w;    w += pad256((size_t)(N + 1) * 4);
    int*   srcs       = (int*)w;    w += pad256((size_t)E * 4);
    int*   e2p        = (int*)w;    w += pad256((size_t)E * 4);
    int*   blkCount   = (int*)w;    w += pad256((size_t)MAXNB * NBLK * 4);
    int*   bucketBase = (int*)w;    w += pad256((size_t)(MAXNB + 1) * 4);
    float* gsum       = (float*)w;  w += pad256((size_t)NG * D * 4);
    float* gcnt       = (float*)w;  w += pad256((size_t)NG * 4);

    hipMemsetAsync(gsum, 0, (size_t)NG * D * 4, stream);
    hipMemsetAsync(gcnt, 0, (size_t)NG * 4, stream);

    const int* e_src = ei;
    const int* e_dst = ei + E;

    k_bcount<<<NBLK, 256, 0, stream>>>(e_dst, E, NB, blkCount);
    k_bbase<<<1, 512, 0, stream>>>(blkCount, NB, E, bucketBase);
    k_bplace<<<NBLK, 256, 0, stream>>>(e_src, e_dst, E, NB, blkCount, e2p);
    k_csrdeg<<<NB, 256, 0, stream>>>(e2p, bucketBase, N, E, rowptr, dinv, srcs);

    k_xw1<<<(N + 63) / 64, 256, 0, stream>>>(x, W1, dinv, N, hs4);

    {
        long long threads = (long long)N * 64;
        int blocks = (int)((threads + 255) / 256);
        k_gather<<<blocks, 256, 0, stream>>>(hs4, dinv, rowptr, srcs, b1, N, r4);
    }
    {
        int waves = (N + NPW - 1) / NPW;
        long long threads = (long long)waves * 64;
        int blocks = (int)((threads + 255) / 256);
        k_pool<<<blocks, 256, 0, stream>>>(r4, batch, N, gsum, gcnt);
    }
    k_head<<<1, 128, 0, stream>>>(gsum, gcnt, W2, b2, out);
}